// Round 5
// baseline (1302.678 us; speedup 1.0000x reference)
//
#include <hip/hip_runtime.h>
#include <cstdint>
#include <cstddef>

// ---------------------------------------------------------------------------
// Pointer-network decoder: B=128 batches decode T=32 steps over N=512 nodes.
// One block per batch (grid 128 <= 256 CUs: every block owns a full CU).
// Round 7: Whh register-resident. Round 4 proved wg=512 + waves_per_eu(2,2)
// yields a working >=128-VGPR budget (spill-free at 128); at 2 waves/SIMD
// the cap is 256, so thread j additionally holds Whh[j,0..127] in 32 named
// float4 (128 VGPRs). P1's Whh half is now pure reg-FMA: per-step L2 weight
// stream drops 576 KB -> 320 KB (Wih 256 + W2T 64) and its load-issue cost
// disappears. encT2 split unchanged: k=0..63 in 16 named float4, k=64..127
// in 128KB dynamic LDS. All accumulation orders preserved (a0h/a1h same
// MACs, same ascending h, same final combine) -> bit-identical (absmax 0).
// Sampling reproduces jax.random.categorical bit-exactly (threefry2x32).
// Tell for success: VGPR ~220-256 with WRITE_SIZE ~32 KB (no spill).
// ---------------------------------------------------------------------------

constexpr int B = 128, N = 512, H = 128, T = 32;
constexpr int G4 = 4 * H;  // 512
constexpr float TINYF = 1.17549435e-38f;  // np.finfo(float32).tiny

// ---- JAX threefry2x32 block cipher (20 rounds) ----------------------------
__host__ __device__ inline uint32_t rotl32(uint32_t v, int d) {
  return (v << d) | (v >> (32 - d));
}

__host__ __device__ inline void tf2x32(uint32_t k0, uint32_t k1,
                                       uint32_t x0, uint32_t x1,
                                       uint32_t& o0, uint32_t& o1) {
  uint32_t ks2 = k0 ^ k1 ^ 0x1BD11BDAu;
  x0 += k0; x1 += k1;
#define TF_R(r) x0 += x1; x1 = rotl32(x1, (r)); x1 ^= x0;
  TF_R(13) TF_R(15) TF_R(26) TF_R(6)
  x0 += k1; x1 += ks2 + 1u;
  TF_R(17) TF_R(29) TF_R(16) TF_R(24)
  x0 += ks2; x1 += k0 + 2u;
  TF_R(13) TF_R(15) TF_R(26) TF_R(6)
  x0 += k0; x1 += k1 + 3u;
  TF_R(17) TF_R(29) TF_R(16) TF_R(24)
  x0 += k1; x1 += ks2 + 4u;
  TF_R(13) TF_R(15) TF_R(26) TF_R(6)
  x0 += ks2; x1 += k0 + 5u;
#undef TF_R
  o0 = x0; o1 = x1;
}

struct KeyArgs { uint32_t k[2 * T]; };  // per-step subkeys, 256 B by value

// Host-side key chain (partitionable split): key0 = (0,42);
// new_key = E_key(0,0), sub = E_key(0,1).
static KeyArgs make_subkeys() {
  KeyArgs ka;
  uint32_t k0 = 0u, k1 = 42u;
  for (int t = 0; t < T; ++t) {
    uint32_t n0, n1, s0, s1;
    tf2x32(k0, k1, 0u, 0u, n0, n1);
    tf2x32(k0, k1, 0u, 1u, s0, s1);
    ka.k[2 * t] = s0; ka.k[2 * t + 1] = s1;
    k0 = n0; k1 = n1;
  }
  return ka;
}

// 32-bit draw i (of 65536) for this step's subkey: w0^w1 of E_sub(0, i)
__device__ inline uint32_t gumbel_bits(uint32_t sk0, uint32_t sk1, int i) {
  uint32_t o0, o1;
  tf2x32(sk0, sk1, 0u, (uint32_t)i, o0, o1);
  return o0 ^ o1;
}

// fast tanh for the score hot loop; abs err ~2e-7 (clamp avoids inf/inf NaN)
__device__ inline float fast_tanh(float x) {
  float cx = fminf(9.0f, fmaxf(-9.0f, x));
  float t = __expf(2.0f * cx);
  return (t - 1.0f) * __builtin_amdgcn_rcpf(t + 1.0f);
}

// ---- setup kernel 1: transpose weights for coalesced access ---------------
__global__ void k_transpose(const float* __restrict__ Wih, const float* __restrict__ Whh,
                            const float* __restrict__ W2, const float* __restrict__ W1,
                            float* __restrict__ WihT, float* __restrict__ WhhT,
                            float* __restrict__ W2T, float* __restrict__ W1T) {
  int i = blockIdx.x * blockDim.x + threadIdx.x;
  if (i < H * G4) {
    int h = i >> 9, j = i & (G4 - 1);
    WihT[i] = Wih[j * H + h];
  } else if (i < 2 * H * G4) {
    int q = i - H * G4; int h = q >> 9, j = q & (G4 - 1);
    WhhT[q] = Whh[j * H + h];
  } else if (i < 2 * H * G4 + H * H) {
    int q = i - 2 * H * G4; int h = q >> 7, k = q & (H - 1);
    W2T[q] = W2[k * H + h];
  } else if (i < 2 * H * G4 + 2 * H * H) {
    int q = i - 2 * H * G4 - H * H; int h = q >> 7, k = q & (H - 1);
    W1T[q] = W1[k * H + h];
  }
}

// ---- setup kernel 2: encT2[b,k,n] = sum_h enc[b,n,h] * W1[k,h] ------------
// (k-major output for the decode score SGEMV). 16 enc rows staged in LDS;
// 256 threads = 128 k x 2 n-groups; per-thread 8 consecutive n -> 2x float4.
__global__ __launch_bounds__(256) void k_enc_trans(const float* __restrict__ enc,
                                                   const float* __restrict__ W1T,
                                                   float* __restrict__ encT2) {
  __shared__ __align__(16) float es[16 * 128];  // 8 KB
  int blk = blockIdx.x;
  int b = blk >> 5;               // 32 blocks per batch
  int n0 = (blk & 31) << 4;       // 16 rows
  const float* src = enc + ((size_t)b * N + n0) * H;
  for (int i = threadIdx.x; i < 16 * 128; i += 256) es[i] = src[i];
  __syncthreads();
  int k = threadIdx.x & 127, ng = threadIdx.x >> 7;
  float acc[8] = {0.f, 0.f, 0.f, 0.f, 0.f, 0.f, 0.f, 0.f};
  for (int h = 0; h < H; h += 4) {
    float w0 = W1T[(h + 0) * H + k];   // coalesced (lanes = consecutive k)
    float w1 = W1T[(h + 1) * H + k];
    float w2 = W1T[(h + 2) * H + k];
    float w3 = W1T[(h + 3) * H + k];
#pragma unroll
    for (int j = 0; j < 8; ++j) {
      const float4 e = *(const float4*)&es[(ng * 8 + j) * 128 + h];  // broadcast
      acc[j] += w0 * e.x + w1 * e.y + w2 * e.z + w3 * e.w;
    }
  }
  float* dst = encT2 + (size_t)b * H * N + (size_t)k * N + n0 + ng * 8;
  ((float4*)dst)[0] = make_float4(acc[0], acc[1], acc[2], acc[3]);
  ((float4*)dst)[1] = make_float4(acc[4], acc[5], acc[6], acc[7]);
}

#define REP16(M) M(0) M(1) M(2) M(3) M(4) M(5) M(6) M(7) \
                 M(8) M(9) M(10) M(11) M(12) M(13) M(14) M(15)
#define REP16A(M) M(0) M(1) M(2) M(3) M(4) M(5) M(6) M(7) \
                  M(8) M(9) M(10) M(11) M(12) M(13) M(14) M(15)
#define REP16B(M) M(16) M(17) M(18) M(19) M(20) M(21) M(22) M(23) \
                  M(24) M(25) M(26) M(27) M(28) M(29) M(30) M(31)

// ---- main fused decoder: 1 block per batch, 512 threads (8 waves) ---------
// Dynamic LDS (128 KB): e_lds[64][512] = encT2[b][64..127][:] (k-half 1).
// Registers: er0..er15 (encT2 k 0..63 for node tid) + wh0..wh31
// (Whh[tid][0..127]) = 192 persistent VGPRs; cap 256 at 2 waves/EU.
__global__ __launch_bounds__(512)
__attribute__((amdgpu_waves_per_eu(2, 2))) void k_decode(
    const float* __restrict__ enc, const float* __restrict__ encT2,
    const float* __restrict__ WihT, const float* __restrict__ WhhT,
    const float* __restrict__ W2T,
    const float* __restrict__ bih, const float* __restrict__ bhh,
    const float* __restrict__ v,
    KeyArgs keys, float* __restrict__ out) {
  __shared__ __align__(16) float xs[H];     // dec_input
  __shared__ __align__(16) float hs[H];     // hx
  __shared__ __align__(16) float cs[H];     // cx
  __shared__ __align__(16) float dt[H];     // dec_trans = hx @ W2^T
  __shared__ __align__(16) float vv[H];
  __shared__ __align__(16) float bsum[G4];  // b_ih + b_hh
  __shared__ float pg[G4];                  // gate pre-activations (sans bias)
  __shared__ float pdt[4][H];               // dt partials (and init-mean partials)
  __shared__ float sc[N];                   // masked scores (P6b reads sc[s_idx])
  __shared__ float wr_z[8], wr_m[8], wr_s[8];
  __shared__ int wr_i[8];
  __shared__ float s_smax;
  __shared__ int s_idx;

  extern __shared__ __align__(16) float e_lds[];  // 64*512 floats = 128 KB

  const int tid = threadIdx.x;   // owns node n = tid and gate j = tid
  const int b = blockIdx.x;
  const int lane = tid & 63;
  const int wave = tid >> 6;     // 0..7

  // ---- register-stage encT2[b][0..63][tid]: 16 named float4 (no alloca) ---
  const float* ep = encT2 + (size_t)b * (H * N) + tid;
#define ERLD(i) float4 er##i = make_float4(ep[(size_t)(4*i+0) * N], \
                                           ep[(size_t)(4*i+1) * N], \
                                           ep[(size_t)(4*i+2) * N], \
                                           ep[(size_t)(4*i+3) * N]);
  REP16(ERLD)
#undef ERLD

  // ---- register-stage Whh[tid][0..127]: 32 named float4 (128 VGPRs) -------
  // (coalesced: lanes = consecutive tid for each fixed h)
  const float* wp = WhhT + tid;
#define WHLD(i) float4 wh##i = make_float4(wp[(size_t)(4*i+0) * G4], \
                                           wp[(size_t)(4*i+1) * G4], \
                                           wp[(size_t)(4*i+2) * G4], \
                                           wp[(size_t)(4*i+3) * G4]);
  REP16A(WHLD)
  REP16B(WHLD)
#undef WHLD

  // ---- LDS-stage encT2[b][64..127][:] (128 KB), coalesced float4 ----------
  {
    const float4* src4 = (const float4*)(encT2 + (size_t)b * (H * N) + (size_t)64 * N);
    float4* dst4 = (float4*)e_lds;
#pragma unroll
    for (int i = 0; i < 16; ++i) dst4[tid + i * 512] = src4[tid + i * 512];
  }

  // ---- init: dec_input = mean_n enc[b,n,:]; h = c = 0 ----
  {
    int h = tid & 127, part = tid >> 7;
    float s = 0.f;
    const float* p = enc + ((size_t)b * N + part * 128) * H + h;
#pragma unroll 8
    for (int n = 0; n < 128; ++n) s += p[(size_t)n * H];  // coalesced across h
    pdt[part][h] = s;
    bsum[tid] = bih[tid] + bhh[tid];
  }
  if (tid < 128) { hs[tid] = 0.f; cs[tid] = 0.f; vv[tid] = v[tid]; }
  __syncthreads();
  if (tid < 128)
    xs[tid] = (pdt[0][tid] + pdt[1][tid] + pdt[2][tid] + pdt[3][tid]) * (1.0f / N);
  bool masked = false;  // thread tid owns node tid
  __syncthreads();

  for (int t = 0; t < T; ++t) {
    // --- P1: full gate j = tid. Wih streamed from L2 (a0x: h 0..63,
    // a1x: h 64..127); Whh from registers (a0h: h 0..63, a1h: h 64..127).
    // Each accumulator's MAC sequence is ascending-h, identical to round 6;
    // final (a0x+a0h)+(a1x+a1h) unchanged -> bitwise identical gates. -------
    {
      const float* wi = WihT + tid;
      float a0x = 0.f, a0h = 0.f, a1x = 0.f, a1h = 0.f;
#pragma unroll 8
      for (int h = 0; h < 64; h += 4) {
        const float4 xv = *(const float4*)&xs[h];
        a0x += wi[(size_t)(h + 0) * G4] * xv.x;
        a0x += wi[(size_t)(h + 1) * G4] * xv.y;
        a0x += wi[(size_t)(h + 2) * G4] * xv.z;
        a0x += wi[(size_t)(h + 3) * G4] * xv.w;
      }
#pragma unroll 8
      for (int h = 64; h < 128; h += 4) {
        const float4 xv = *(const float4*)&xs[h];
        a1x += wi[(size_t)(h + 0) * G4] * xv.x;
        a1x += wi[(size_t)(h + 1) * G4] * xv.y;
        a1x += wi[(size_t)(h + 2) * G4] * xv.z;
        a1x += wi[(size_t)(h + 3) * G4] * xv.w;
      }
      // Whh part from registers: wh_i covers h = 4i..4i+3
#define WHMACA(i) { const float4 hv = *(const float4*)&hs[4 * (i)];         \
                    a0h += wh##i.x * hv.x;  a0h += wh##i.y * hv.y;          \
                    a0h += wh##i.z * hv.z;  a0h += wh##i.w * hv.w; }
      REP16A(WHMACA)
#undef WHMACA
#define WHMACB(i) { const float4 hv = *(const float4*)&hs[4 * (i)];         \
                    a1h += wh##i.x * hv.x;  a1h += wh##i.y * hv.y;          \
                    a1h += wh##i.z * hv.z;  a1h += wh##i.w * hv.w; }
      REP16B(WHMACB)
#undef WHMACB
      pg[tid] = (a0x + a0h) + (a1x + a1h);
    }
    __syncthreads();
    // --- P2: cell update (torch gate order i,f,g,o) -------------------------
    if (tid < 128) {
      float gi = pg[tid] + bsum[tid];
      float gf = pg[H + tid] + bsum[H + tid];
      float gg = pg[2 * H + tid] + bsum[2 * H + tid];
      float go = pg[3 * H + tid] + bsum[3 * H + tid];
      gi = 1.0f / (1.0f + expf(-gi));
      gf = 1.0f / (1.0f + expf(-gf));
      gg = tanhf(gg);
      go = 1.0f / (1.0f + expf(-go));
      float c = gf * cs[tid] + gi * gg;
      cs[tid] = c;
      hs[tid] = go * tanhf(c);
    }
    __syncthreads();
    // --- P3: dt partials: k = tid&127, 32 h each ----------------------------
    {
      int k = tid & 127, part = tid >> 7;
      const float* w2 = W2T + (size_t)(part * 32) * H + k;
      const int hbp = part * 32;
      float a = 0.f;
#pragma unroll 8
      for (int h = 0; h < 32; h += 4) {
        const float4 hv = *(const float4*)&hs[hbp + h];
        a += w2[(size_t)(h + 0) * H] * hv.x;
        a += w2[(size_t)(h + 1) * H] * hv.y;
        a += w2[(size_t)(h + 2) * H] * hv.z;
        a += w2[(size_t)(h + 3) * H] * hv.w;
      }
      pdt[part][k] = a;
    }
    __syncthreads();
    if (tid < 128) dt[tid] = pdt[0][tid] + pdt[1][tid] + pdt[2][tid] + pdt[3][tid];
    __syncthreads();
    // --- P4 + P5a fused: full score for node n = tid, then gumbel/argmax ----
    // k-half 0 from registers, k-half 1 from LDS; accumulator pattern
    // (a0 = k%4 in {0,2}, a1 = k%4 in {1,3}, ascending k, per half, then
    // (a0+a1) + (b0+b1)) is bitwise == round 6.
    float s_score;
    {
      float a0 = 0.f, a1 = 0.f;
#define P4A(i) { const float4 dv = *(const float4*)&dt[4 * i];              \
                 const float4 vw = *(const float4*)&vv[4 * i];              \
                 a0 += vw.x * fast_tanh(er##i.x + dv.x);                    \
                 a1 += vw.y * fast_tanh(er##i.y + dv.y);                    \
                 a0 += vw.z * fast_tanh(er##i.z + dv.z);                    \
                 a1 += vw.w * fast_tanh(er##i.w + dv.w); }
      REP16(P4A)
#undef P4A
      float b0 = 0.f, b1 = 0.f;
#pragma unroll
      for (int k4 = 0; k4 < 64; k4 += 4) {
        const float e0 = e_lds[(k4 + 0) * N + tid];
        const float e1 = e_lds[(k4 + 1) * N + tid];
        const float e2 = e_lds[(k4 + 2) * N + tid];
        const float e3 = e_lds[(k4 + 3) * N + tid];
        const float4 dv = *(const float4*)&dt[64 + k4];
        const float4 vw = *(const float4*)&vv[64 + k4];
        b0 += vw.x * fast_tanh(e0 + dv.x);
        b1 += vw.y * fast_tanh(e1 + dv.y);
        b0 += vw.z * fast_tanh(e2 + dv.z);
        b1 += vw.w * fast_tanh(e3 + dv.w);
      }
      s_score = (a0 + a1) + (b0 + b1);
    }
    // P5a: mask, gumbel, per-wave argmax + score max (all 8 waves active)
    float s = masked ? -INFINITY : s_score;
    sc[tid] = s;
    {
      uint32_t bits = gumbel_bits(keys.k[2 * t], keys.k[2 * t + 1], b * N + tid);
      // XLA uniform(minval=tiny, maxval=1): bits->[1,2)->-1, +tiny, max
      float f = __uint_as_float((bits >> 9) | 0x3f800000u) - 1.0f;
      float u = fmaxf(TINYF, f + TINYF);
      float g = -logf(-logf(u));  // accurate logf (hw log2 too sloppy near u~1)
      float z = s + g;
      int zi = tid;
      float m = s;
#pragma unroll
      for (int d = 32; d >= 1; d >>= 1) {
        float oz = __shfl_xor(z, d);
        int oi = __shfl_xor(zi, d);
        float om = __shfl_xor(m, d);
        if (oz > z || (oz == z && oi < zi)) { z = oz; zi = oi; }  // first-idx ties
        m = fmaxf(m, om);
      }
      if (lane == 0) { wr_z[wave] = z; wr_i[wave] = zi; wr_m[wave] = m; }
    }
    __syncthreads();
    // --- P5b: final argmax + max over the 8 waves ---------------------------
    if (tid == 0) {
      float bz = wr_z[0]; int bi = wr_i[0]; float bm = wr_m[0];
#pragma unroll
      for (int w = 1; w < 8; ++w) {
        if (wr_z[w] > bz || (wr_z[w] == bz && wr_i[w] < bi)) { bz = wr_z[w]; bi = wr_i[w]; }
        bm = fmaxf(bm, wr_m[w]);
      }
      s_idx = bi; s_smax = bm;
    }
    __syncthreads();
    // --- P6: softmax denom; mask update; next dec_input ---------------------
    {
      float xnew = 0.f;
      if (tid < 128) xnew = enc[((size_t)b * N + s_idx) * H + tid];  // issue early
      float e = expf(s - s_smax);  // masked: exp(-inf) = 0
#pragma unroll
      for (int d = 32; d >= 1; d >>= 1) e += __shfl_xor(e, d);
      if (lane == 0) wr_s[wave] = e;
      if (tid == s_idx) masked = true;
      if (tid < 128) xs[tid] = xnew;
    }
    __syncthreads();
    // --- P6b: outputs (no barrier needed: writes global only) ---------------
    if (tid == 0) {
      float sum = wr_s[0] + wr_s[1] + wr_s[2] + wr_s[3]
                + wr_s[4] + wr_s[5] + wr_s[6] + wr_s[7];
      float p = expf(sc[s_idx] - s_smax) / sum;
      out[(size_t)b * T + t] = (float)s_idx;                       // tours [B,T]
      out[(size_t)B * T + (size_t)b * T + t] = logf(p + 1e-9f);    // log_probs
    }
    __syncthreads();
  }
}

// ---------------------------------------------------------------------------
extern "C" void kernel_launch(void* const* d_in, const int* in_sizes, int n_in,
                              void* d_out, int out_size, void* d_ws, size_t ws_size,
                              hipStream_t stream) {
  (void)in_sizes; (void)n_in; (void)out_size; (void)ws_size;
  const float* enc = (const float*)d_in[0];
  const float* Wih = (const float*)d_in[1];
  const float* Whh = (const float*)d_in[2];
  const float* bih = (const float*)d_in[3];
  const float* bhh = (const float*)d_in[4];
  const float* W1  = (const float*)d_in[5];
  const float* W2  = (const float*)d_in[6];
  const float* v   = (const float*)d_in[7];
  float* out = (float*)d_out;
  float* ws = (float*)d_ws;

  // ws layout (floats): WihT 65536 | WhhT 65536 | W2T 16384 | W1T 16384 | encT2 8388608
  float* WihT  = ws;
  float* WhhT  = ws + 65536;
  float* W2T   = ws + 131072;
  float* W1T   = ws + 147456;
  float* encT2 = ws + 163840;   // [b][k][n], ~33.5 MB

  KeyArgs keys = make_subkeys();  // pure host arithmetic: capture-safe

  // allow 128KB dynamic LDS for k_decode (host-side attr; capture-safe)
  static bool lds_attr_set = false;
  if (!lds_attr_set) {
    (void)hipFuncSetAttribute(reinterpret_cast<const void*>(k_decode),
                              hipFuncAttributeMaxDynamicSharedMemorySize, 131072);
    lds_attr_set = true;
  }

  k_transpose<<<640, 256, 0, stream>>>(Wih, Whh, W2, W1, WihT, WhhT, W2T, W1T);
  k_enc_trans<<<B * N / 16, 256, 0, stream>>>(enc, W1T, encT2);
  k_decode<<<B, 512, 131072, stream>>>(enc, encT2, WihT, WhhT, W2T, bih, bhh, v, keys, out);
}

// Round 6
// 853.486 us; speedup vs baseline: 1.5263x; 1.5263x over previous
//
#include <hip/hip_runtime.h>
#include <cstdint>
#include <cstddef>

// ---------------------------------------------------------------------------
// Pointer-network decoder: B=128 batches decode T=32 steps over N=512 nodes.
// Round 8: TWO batches per block (grid 64 x 1024 threads, half = tid>>9).
// Rationale: rounds 0 vs 4 proved the step time is NOT stream-bound (removing
// 256KB/step of L2 traffic bought 3%); it is VALU + barrier-serialized
// latency on a half-idle chip. Two independent batches sharing one block's
// barrier chain double the per-CU independent work: every barrier serves 2
// batches, serial sections run in parallel in disjoint thread ranges, and
// P1/P3 compute BOTH batches' GEMVs off one shared weight load (tid<512).
// VGPR envelope (learned rounds 1-5): wg=1024 -> 64 regs, wg=512 -> 128,
// never more. This design needs no register staging (round-0-style streams,
// encT2 rows 0..31/batch in 128KB dynamic LDS for L2-capacity fit).
// All per-batch FMA orders/accumulator splits identical to round 4 ->
// bit-identical outputs (absmax 0.0). threefry sampling bit-exact.
// ---------------------------------------------------------------------------

constexpr int B = 128, N = 512, H = 128, T = 32;
constexpr int G4 = 4 * H;  // 512
constexpr float TINYF = 1.17549435e-38f;  // np.finfo(float32).tiny

// ---- JAX threefry2x32 block cipher (20 rounds) ----------------------------
__host__ __device__ inline uint32_t rotl32(uint32_t v, int d) {
  return (v << d) | (v >> (32 - d));
}

__host__ __device__ inline void tf2x32(uint32_t k0, uint32_t k1,
                                       uint32_t x0, uint32_t x1,
                                       uint32_t& o0, uint32_t& o1) {
  uint32_t ks2 = k0 ^ k1 ^ 0x1BD11BDAu;
  x0 += k0; x1 += k1;
#define TF_R(r) x0 += x1; x1 = rotl32(x1, (r)); x1 ^= x0;
  TF_R(13) TF_R(15) TF_R(26) TF_R(6)
  x0 += k1; x1 += ks2 + 1u;
  TF_R(17) TF_R(29) TF_R(16) TF_R(24)
  x0 += ks2; x1 += k0 + 2u;
  TF_R(13) TF_R(15) TF_R(26) TF_R(6)
  x0 += k0; x1 += k1 + 3u;
  TF_R(17) TF_R(29) TF_R(16) TF_R(24)
  x0 += k1; x1 += ks2 + 4u;
  TF_R(13) TF_R(15) TF_R(26) TF_R(6)
  x0 += ks2; x1 += k0 + 5u;
#undef TF_R
  o0 = x0; o1 = x1;
}

struct KeyArgs { uint32_t k[2 * T]; };  // per-step subkeys, 256 B by value

// Host-side key chain (partitionable split): key0 = (0,42);
// new_key = E_key(0,0), sub = E_key(0,1).
static KeyArgs make_subkeys() {
  KeyArgs ka;
  uint32_t k0 = 0u, k1 = 42u;
  for (int t = 0; t < T; ++t) {
    uint32_t n0, n1, s0, s1;
    tf2x32(k0, k1, 0u, 0u, n0, n1);
    tf2x32(k0, k1, 0u, 1u, s0, s1);
    ka.k[2 * t] = s0; ka.k[2 * t + 1] = s1;
    k0 = n0; k1 = n1;
  }
  return ka;
}

// 32-bit draw i (of 65536) for this step's subkey: w0^w1 of E_sub(0, i)
__device__ inline uint32_t gumbel_bits(uint32_t sk0, uint32_t sk1, int i) {
  uint32_t o0, o1;
  tf2x32(sk0, sk1, 0u, (uint32_t)i, o0, o1);
  return o0 ^ o1;
}

// fast tanh for the score hot loop; abs err ~2e-7 (clamp avoids inf/inf NaN)
__device__ inline float fast_tanh(float x) {
  float cx = fminf(9.0f, fmaxf(-9.0f, x));
  float t = __expf(2.0f * cx);
  return (t - 1.0f) * __builtin_amdgcn_rcpf(t + 1.0f);
}

// ---- setup kernel 1: transpose weights for coalesced access ---------------
__global__ void k_transpose(const float* __restrict__ Wih, const float* __restrict__ Whh,
                            const float* __restrict__ W2, const float* __restrict__ W1,
                            float* __restrict__ WihT, float* __restrict__ WhhT,
                            float* __restrict__ W2T, float* __restrict__ W1T) {
  int i = blockIdx.x * blockDim.x + threadIdx.x;
  if (i < H * G4) {
    int h = i >> 9, j = i & (G4 - 1);
    WihT[i] = Wih[j * H + h];
  } else if (i < 2 * H * G4) {
    int q = i - H * G4; int h = q >> 9, j = q & (G4 - 1);
    WhhT[q] = Whh[j * H + h];
  } else if (i < 2 * H * G4 + H * H) {
    int q = i - 2 * H * G4; int h = q >> 7, k = q & (H - 1);
    W2T[q] = W2[k * H + h];
  } else if (i < 2 * H * G4 + 2 * H * H) {
    int q = i - 2 * H * G4 - H * H; int h = q >> 7, k = q & (H - 1);
    W1T[q] = W1[k * H + h];
  }
}

// ---- setup kernel 2: encT2[b,k,n] = sum_h enc[b,n,h] * W1[k,h] ------------
// (k-major output for the decode score SGEMV). 16 enc rows staged in LDS;
// 256 threads = 128 k x 2 n-groups; per-thread 8 consecutive n -> 2x float4.
__global__ __launch_bounds__(256) void k_enc_trans(const float* __restrict__ enc,
                                                   const float* __restrict__ W1T,
                                                   float* __restrict__ encT2) {
  __shared__ __align__(16) float es[16 * 128];  // 8 KB
  int blk = blockIdx.x;
  int b = blk >> 5;               // 32 blocks per batch
  int n0 = (blk & 31) << 4;       // 16 rows
  const float* src = enc + ((size_t)b * N + n0) * H;
  for (int i = threadIdx.x; i < 16 * 128; i += 256) es[i] = src[i];
  __syncthreads();
  int k = threadIdx.x & 127, ng = threadIdx.x >> 7;
  float acc[8] = {0.f, 0.f, 0.f, 0.f, 0.f, 0.f, 0.f, 0.f};
  for (int h = 0; h < H; h += 4) {
    float w0 = W1T[(h + 0) * H + k];   // coalesced (lanes = consecutive k)
    float w1 = W1T[(h + 1) * H + k];
    float w2 = W1T[(h + 2) * H + k];
    float w3 = W1T[(h + 3) * H + k];
#pragma unroll
    for (int j = 0; j < 8; ++j) {
      const float4 e = *(const float4*)&es[(ng * 8 + j) * 128 + h];  // broadcast
      acc[j] += w0 * e.x + w1 * e.y + w2 * e.z + w3 * e.w;
    }
  }
  float* dst = encT2 + (size_t)b * H * N + (size_t)k * N + n0 + ng * 8;
  ((float4*)dst)[0] = make_float4(acc[0], acc[1], acc[2], acc[3]);
  ((float4*)dst)[1] = make_float4(acc[4], acc[5], acc[6], acc[7]);
}

// ---- main fused decoder: 2 batches per block, 1024 threads (16 waves) -----
// half = tid>>9 selects the batch (b = blockIdx + 64*half).
// Dynamic LDS (128 KB): e_lds[half][32][512] = encT2[b][0..31][:].
// P1/P3: tid<512 compute BOTH batches' GEMVs sharing each weight load.
__global__ __launch_bounds__(1024) void k_decode(
    const float* __restrict__ enc, const float* __restrict__ encT2,
    const float* __restrict__ WihT, const float* __restrict__ WhhT,
    const float* __restrict__ W2T,
    const float* __restrict__ bih, const float* __restrict__ bhh,
    const float* __restrict__ v,
    KeyArgs keys, float* __restrict__ out) {
  __shared__ __align__(16) float xs[2][H];   // dec_input (per batch)
  __shared__ __align__(16) float hs[2][H];   // hx
  __shared__ __align__(16) float cs[2][H];   // cx
  __shared__ __align__(16) float dt[2][H];   // dec_trans = hx @ W2^T
  __shared__ __align__(16) float vv[H];
  __shared__ __align__(16) float bsum[G4];   // b_ih + b_hh (shared)
  __shared__ float pg[2][G4];                // gate pre-activations
  __shared__ float pdt[2][4][H];             // dt partials (and init-mean)
  __shared__ float sc[2][N];                 // masked scores
  __shared__ float wr_z[2][8], wr_m[2][8], wr_s[2][8];
  __shared__ int wr_i[2][8];
  __shared__ float s_smax[2];
  __shared__ int s_idx[2];

  extern __shared__ __align__(16) float e_lds[];  // 2*32*512 floats = 128 KB

  const int tid = threadIdx.x;
  const int half = tid >> 9;      // batch slot 0/1
  const int id = tid & 511;       // node n / gate j within the batch
  const int lane = tid & 63;
  const int wv = (tid >> 6) & 7;  // wave index within the half
  const int b = blockIdx.x + 64 * half;  // true batch index

  // ---- LDS-stage encT2[b][0..31][:] (64 KB per batch), coalesced float4 ---
  {
    const float4* src4 = (const float4*)(encT2 + (size_t)b * (H * N));
    float4* dst4 = (float4*)e_lds + (size_t)half * 4096;
#pragma unroll
    for (int i = 0; i < 8; ++i) dst4[id + i * 512] = src4[id + i * 512];
  }

  // ---- init: dec_input = mean_n enc[b,n,:]; h = c = 0 ----
  {
    int h = tid & 127, part = (tid >> 7) & 3;
    float s = 0.f;
    const float* p = enc + ((size_t)b * N + part * 128) * H + h;
#pragma unroll 8
    for (int n = 0; n < 128; ++n) s += p[(size_t)n * H];  // coalesced across h
    pdt[half][part][h] = s;
  }
  if (tid < 512) bsum[tid] = bih[tid] + bhh[tid];
  if (id < 128) { hs[half][id] = 0.f; cs[half][id] = 0.f; }
  if (tid < 128) vv[tid] = v[tid];
  __syncthreads();
  if (id < 128)
    xs[half][id] = (pdt[half][0][id] + pdt[half][1][id] +
                    pdt[half][2][id] + pdt[half][3][id]) * (1.0f / N);
  bool masked = false;  // thread owns node id of batch half
  __syncthreads();

  for (int t = 0; t < T; ++t) {
    // --- P1: gates for BOTH batches, gate j = tid (tid<512 only). Each
    // weight scalar loaded once, FMA'd into batch0 and batch1 accumulators.
    // Per-batch accumulator pattern (a0x: h0..63 asc, a1x: h64..127, a0h,
    // a1h; combine (a0x+a0h)+(a1x+a1h)) is bitwise == round 4. -------------
    if (tid < 512) {
      const float* wi = WihT + tid;
      const float* wh = WhhT + tid;
      float a0x0 = 0.f, a0h0 = 0.f, a1x0 = 0.f, a1h0 = 0.f;
      float a0x1 = 0.f, a0h1 = 0.f, a1x1 = 0.f, a1h1 = 0.f;
#pragma unroll 4
      for (int h = 0; h < 64; h += 4) {
        const float w0 = wi[(size_t)(h + 0) * G4];
        const float w1 = wi[(size_t)(h + 1) * G4];
        const float w2 = wi[(size_t)(h + 2) * G4];
        const float w3 = wi[(size_t)(h + 3) * G4];
        const float4 x0 = *(const float4*)&xs[0][h];
        const float4 x1 = *(const float4*)&xs[1][h];
        a0x0 += w0 * x0.x; a0x0 += w1 * x0.y; a0x0 += w2 * x0.z; a0x0 += w3 * x0.w;
        a0x1 += w0 * x1.x; a0x1 += w1 * x1.y; a0x1 += w2 * x1.z; a0x1 += w3 * x1.w;
        const float u0 = wh[(size_t)(h + 0) * G4];
        const float u1 = wh[(size_t)(h + 1) * G4];
        const float u2 = wh[(size_t)(h + 2) * G4];
        const float u3 = wh[(size_t)(h + 3) * G4];
        const float4 h0 = *(const float4*)&hs[0][h];
        const float4 h1 = *(const float4*)&hs[1][h];
        a0h0 += u0 * h0.x; a0h0 += u1 * h0.y; a0h0 += u2 * h0.z; a0h0 += u3 * h0.w;
        a0h1 += u0 * h1.x; a0h1 += u1 * h1.y; a0h1 += u2 * h1.z; a0h1 += u3 * h1.w;
      }
#pragma unroll 4
      for (int h = 64; h < 128; h += 4) {
        const float w0 = wi[(size_t)(h + 0) * G4];
        const float w1 = wi[(size_t)(h + 1) * G4];
        const float w2 = wi[(size_t)(h + 2) * G4];
        const float w3 = wi[(size_t)(h + 3) * G4];
        const float4 x0 = *(const float4*)&xs[0][h];
        const float4 x1 = *(const float4*)&xs[1][h];
        a1x0 += w0 * x0.x; a1x0 += w1 * x0.y; a1x0 += w2 * x0.z; a1x0 += w3 * x0.w;
        a1x1 += w0 * x1.x; a1x1 += w1 * x1.y; a1x1 += w2 * x1.z; a1x1 += w3 * x1.w;
        const float u0 = wh[(size_t)(h + 0) * G4];
        const float u1 = wh[(size_t)(h + 1) * G4];
        const float u2 = wh[(size_t)(h + 2) * G4];
        const float u3 = wh[(size_t)(h + 3) * G4];
        const float4 h0 = *(const float4*)&hs[0][h];
        const float4 h1 = *(const float4*)&hs[1][h];
        a1h0 += u0 * h0.x; a1h0 += u1 * h0.y; a1h0 += u2 * h0.z; a1h0 += u3 * h0.w;
        a1h1 += u0 * h1.x; a1h1 += u1 * h1.y; a1h1 += u2 * h1.z; a1h1 += u3 * h1.w;
      }
      pg[0][tid] = (a0x0 + a0h0) + (a1x0 + a1h0);
      pg[1][tid] = (a0x1 + a0h1) + (a1x1 + a1h1);
    }
    __syncthreads();
    // --- P2: cell update, both batches (256 threads; torch order i,f,g,o) ---
    if (id < 128) {
      float gi = pg[half][id] + bsum[id];
      float gf = pg[half][H + id] + bsum[H + id];
      float gg = pg[half][2 * H + id] + bsum[2 * H + id];
      float go = pg[half][3 * H + id] + bsum[3 * H + id];
      gi = 1.0f / (1.0f + expf(-gi));
      gf = 1.0f / (1.0f + expf(-gf));
      gg = tanhf(gg);
      go = 1.0f / (1.0f + expf(-go));
      float c = gf * cs[half][id] + gi * gg;
      cs[half][id] = c;
      hs[half][id] = go * tanhf(c);
    }
    __syncthreads();
    // --- P3: dt partials for BOTH batches, shared W2T loads (tid<512) -------
    if (tid < 512) {
      int k = tid & 127, part = tid >> 7;
      const float* w2 = W2T + (size_t)(part * 32) * H + k;
      const int hbp = part * 32;
      float a0 = 0.f, a1 = 0.f;
#pragma unroll 4
      for (int h = 0; h < 32; h += 4) {
        const float w0 = w2[(size_t)(h + 0) * H];
        const float w1 = w2[(size_t)(h + 1) * H];
        const float w2v = w2[(size_t)(h + 2) * H];
        const float w3 = w2[(size_t)(h + 3) * H];
        const float4 h0 = *(const float4*)&hs[0][hbp + h];
        const float4 h1 = *(const float4*)&hs[1][hbp + h];
        a0 += w0 * h0.x; a0 += w1 * h0.y; a0 += w2v * h0.z; a0 += w3 * h0.w;
        a1 += w0 * h1.x; a1 += w1 * h1.y; a1 += w2v * h1.z; a1 += w3 * h1.w;
      }
      pdt[0][part][k] = a0;
      pdt[1][part][k] = a1;
    }
    __syncthreads();
    if (id < 128)
      dt[half][id] = pdt[half][0][id] + pdt[half][1][id] +
                     pdt[half][2][id] + pdt[half][3][id];
    __syncthreads();
    // --- P4 + P5a fused: full score for node n = id of batch half -----------
    // k 0..31 from LDS, k 32..63 from L2 (both into a0/a1), k 64..127 from
    // L2 into b0/b1; pattern (a0 = k%4 in {0,2}, a1 = {1,3}, ascending k,
    // final (a0+a1)+(b0+b1)) is bitwise == round 4.
    float s_score;
    {
      const float* eg = encT2 + (size_t)b * (H * N) + id;
      const float* el = e_lds + (size_t)half * 16384 + id;
      float a0 = 0.f, a1 = 0.f;
#pragma unroll
      for (int k4 = 0; k4 < 32; k4 += 4) {
        const float e0 = el[(k4 + 0) * 512];
        const float e1 = el[(k4 + 1) * 512];
        const float e2 = el[(k4 + 2) * 512];
        const float e3 = el[(k4 + 3) * 512];
        const float4 dv = *(const float4*)&dt[half][k4];
        const float4 vw = *(const float4*)&vv[k4];
        a0 += vw.x * fast_tanh(e0 + dv.x);
        a1 += vw.y * fast_tanh(e1 + dv.y);
        a0 += vw.z * fast_tanh(e2 + dv.z);
        a1 += vw.w * fast_tanh(e3 + dv.w);
      }
#pragma unroll 4
      for (int k4 = 32; k4 < 64; k4 += 4) {
        const float e0 = eg[(size_t)(k4 + 0) * N];
        const float e1 = eg[(size_t)(k4 + 1) * N];
        const float e2 = eg[(size_t)(k4 + 2) * N];
        const float e3 = eg[(size_t)(k4 + 3) * N];
        const float4 dv = *(const float4*)&dt[half][k4];
        const float4 vw = *(const float4*)&vv[k4];
        a0 += vw.x * fast_tanh(e0 + dv.x);
        a1 += vw.y * fast_tanh(e1 + dv.y);
        a0 += vw.z * fast_tanh(e2 + dv.z);
        a1 += vw.w * fast_tanh(e3 + dv.w);
      }
      float b0 = 0.f, b1 = 0.f;
#pragma unroll 4
      for (int k4 = 64; k4 < 128; k4 += 4) {
        const float e0 = eg[(size_t)(k4 + 0) * N];
        const float e1 = eg[(size_t)(k4 + 1) * N];
        const float e2 = eg[(size_t)(k4 + 2) * N];
        const float e3 = eg[(size_t)(k4 + 3) * N];
        const float4 dv = *(const float4*)&dt[half][k4];
        const float4 vw = *(const float4*)&vv[k4];
        b0 += vw.x * fast_tanh(e0 + dv.x);
        b1 += vw.y * fast_tanh(e1 + dv.y);
        b0 += vw.z * fast_tanh(e2 + dv.z);
        b1 += vw.w * fast_tanh(e3 + dv.w);
      }
      s_score = (a0 + a1) + (b0 + b1);
    }
    // P5a: mask, gumbel, per-wave argmax + score max (all 16 waves active;
    // waves 0..7 = batch0, 8..15 = batch1 -- shuffles never cross batches)
    float s = masked ? -INFINITY : s_score;
    sc[half][id] = s;
    {
      uint32_t bits = gumbel_bits(keys.k[2 * t], keys.k[2 * t + 1], b * N + id);
      // XLA uniform(minval=tiny, maxval=1): bits->[1,2)->-1, +tiny, max
      float f = __uint_as_float((bits >> 9) | 0x3f800000u) - 1.0f;
      float u = fmaxf(TINYF, f + TINYF);
      float g = -logf(-logf(u));  // accurate logf (hw log2 too sloppy near u~1)
      float z = s + g;
      int zi = id;
      float m = s;
#pragma unroll
      for (int d = 32; d >= 1; d >>= 1) {
        float oz = __shfl_xor(z, d);
        int oi = __shfl_xor(zi, d);
        float om = __shfl_xor(m, d);
        if (oz > z || (oz == z && oi < zi)) { z = oz; zi = oi; }  // first-idx ties
        m = fmaxf(m, om);
      }
      if (lane == 0) { wr_z[half][wv] = z; wr_i[half][wv] = zi; wr_m[half][wv] = m; }
    }
    __syncthreads();
    // --- P5b: final argmax + max, one serial thread PER BATCH (parallel) ----
    if (id == 0) {
      float bz = wr_z[half][0]; int bi = wr_i[half][0]; float bm = wr_m[half][0];
#pragma unroll
      for (int w = 1; w < 8; ++w) {
        if (wr_z[half][w] > bz || (wr_z[half][w] == bz && wr_i[half][w] < bi)) {
          bz = wr_z[half][w]; bi = wr_i[half][w];
        }
        bm = fmaxf(bm, wr_m[half][w]);
      }
      s_idx[half] = bi; s_smax[half] = bm;
    }
    __syncthreads();
    // --- P6: softmax denom; mask update; next dec_input ---------------------
    {
      float xnew = 0.f;
      if (id < 128) xnew = enc[((size_t)b * N + s_idx[half]) * H + id];  // early
      float e = expf(s - s_smax[half]);  // masked: exp(-inf) = 0
#pragma unroll
      for (int d = 32; d >= 1; d >>= 1) e += __shfl_xor(e, d);
      if (lane == 0) wr_s[half][wv] = e;
      if (id == s_idx[half]) masked = true;
      if (id < 128) xs[half][id] = xnew;
    }
    __syncthreads();
    // --- P6b: outputs, one thread per batch (no barrier before: global-only)-
    if (id == 0) {
      float sum = wr_s[half][0] + wr_s[half][1] + wr_s[half][2] + wr_s[half][3]
                + wr_s[half][4] + wr_s[half][5] + wr_s[half][6] + wr_s[half][7];
      float p = expf(sc[half][s_idx[half]] - s_smax[half]) / sum;
      out[(size_t)b * T + t] = (float)s_idx[half];                 // tours [B,T]
      out[(size_t)B * T + (size_t)b * T + t] = logf(p + 1e-9f);    // log_probs
    }
    __syncthreads();
  }
}

// ---------------------------------------------------------------------------
extern "C" void kernel_launch(void* const* d_in, const int* in_sizes, int n_in,
                              void* d_out, int out_size, void* d_ws, size_t ws_size,
                              hipStream_t stream) {
  (void)in_sizes; (void)n_in; (void)out_size; (void)ws_size;
  const float* enc = (const float*)d_in[0];
  const float* Wih = (const float*)d_in[1];
  const float* Whh = (const float*)d_in[2];
  const float* bih = (const float*)d_in[3];
  const float* bhh = (const float*)d_in[4];
  const float* W1  = (const float*)d_in[5];
  const float* W2  = (const float*)d_in[6];
  const float* v   = (const float*)d_in[7];
  float* out = (float*)d_out;
  float* ws = (float*)d_ws;

  // ws layout (floats): WihT 65536 | WhhT 65536 | W2T 16384 | W1T 16384 | encT2 8388608
  float* WihT  = ws;
  float* WhhT  = ws + 65536;
  float* W2T   = ws + 131072;
  float* W1T   = ws + 147456;
  float* encT2 = ws + 163840;   // [b][k][n], ~33.5 MB

  KeyArgs keys = make_subkeys();  // pure host arithmetic: capture-safe

  // allow 128KB dynamic LDS for k_decode (host-side attr; capture-safe)
  static bool lds_attr_set = false;
  if (!lds_attr_set) {
    (void)hipFuncSetAttribute(reinterpret_cast<const void*>(k_decode),
                              hipFuncAttributeMaxDynamicSharedMemorySize, 131072);
    lds_attr_set = true;
  }

  k_transpose<<<640, 256, 0, stream>>>(Wih, Whh, W2, W1, WihT, WhhT, W2T, W1T);
  k_enc_trans<<<B * N / 16, 256, 0, stream>>>(enc, W1T, encT2);
  k_decode<<<B / 2, 1024, 131072, stream>>>(enc, encT2, WihT, WhhT, W2T,
                                            bih, bhh, v, keys, out);
}